// Round 3
// baseline (8152.225 us; speedup 1.0000x reference)
//
#include <hip/hip_runtime.h>
#include <hip/hip_cooperative_groups.h>
#include <cstdint>
#include <cstddef>

namespace cg = cooperative_groups;

typedef __attribute__((ext_vector_type(8))) short short8;
typedef __attribute__((ext_vector_type(4))) short short4v;
typedef __attribute__((ext_vector_type(4))) float float4v;

#define T_STEPS 512
#define BATCH   64
#define IN_DIM  512
#define HID     1024
#define BH      (BATCH * HID)              /* 65536 */
#define OPS_SZ  ((size_t)T_STEPS * BH)     /* 33554432 */
#define NX      ((size_t)T_STEPS * BATCH * IN_DIM) /* 16777216 */
#define NWG     256
#define NTHR    1024
#define BAR_BYTES 2048
#define RLX __ATOMIC_RELAXED
#define AGT __HIP_MEMORY_SCOPE_AGENT

__device__ __forceinline__ float bf2f(unsigned short b) {
    return __builtin_bit_cast(float, ((unsigned)b) << 16);
}
__device__ __forceinline__ short f2bf(float f) {
    unsigned u = __builtin_bit_cast(unsigned, f);
    unsigned r = (u + 0x7FFFu + ((u >> 16) & 1u)) >> 16;   // round-nearest-even
    return (short)(unsigned short)r;
}
__device__ __forceinline__ float sigmoidf_(float v) { return 1.0f / (1.0f + __expf(-v)); }

// h WRITE path: agent-scope (bypasses L1/L2, lands in L3 = coherence point).
__device__ __forceinline__ void cohstore_h(short* p, short v) {
    __hip_atomic_store((unsigned short*)p, (unsigned short)v, RLX, AGT);
}
__device__ __forceinline__ unsigned short cohload_h(const short* p) {
    return __hip_atomic_load((unsigned short*)p, RLX, AGT);
}

// ---- Sequenced event barrier (split arrive/wait) ----
// bar layout (dwords): sub slots: [g*32 + (e&3)] for group g = wg>>5 (ring of 4
// per-event counters, 128B apart across groups); groupDone watermarks at
// [260+g]; go watermark at [288].  Events are globally sequenced; a WG can be
// at most ~3 events ahead of the slowest (every arrive(e) is preceded by
// wait(e-2) or stronger), so the 4-deep slot ring never aliases live events.
__device__ __forceinline__ void bar_arrive(unsigned* bar, int wg, unsigned e)
{
    unsigned* slot = bar + (wg >> 5) * 32 + (e & 3u);
    unsigned v = __hip_atomic_fetch_add(slot, 1u, RLX, AGT);
    if (v == 31u) {                     // this group completed event e exactly
        __hip_atomic_store(slot, 0u, RLX, AGT);          // recycle for e+4
        asm volatile("s_waitcnt vmcnt(0)" ::: "memory"); // reset acked first
        __hip_atomic_store(bar + 260 + (wg >> 5), e, RLX, AGT);
        asm volatile("s_waitcnt vmcnt(0)" ::: "memory"); // publish acked before scan
        unsigned mn = 0xFFFFFFFFu;
#pragma unroll
        for (int g = 0; g < 8; ++g) {
            unsigned d = __hip_atomic_load(bar + 260 + g, RLX, AGT);
            mn = d < mn ? d : mn;
        }
        // wall-clock-last completer sees all >= e -> release guaranteed;
        // earlier completers publish conservative minima (never over-release).
        __hip_atomic_fetch_max(bar + 288, mn, RLX, AGT);
    }
}
__device__ __forceinline__ void bar_wait(unsigned* bar, unsigned e)
{
    while (__hip_atomic_load(bar + 288, RLX, AGT) < e)
        __builtin_amdgcn_s_sleep(1);
}

// ---- GEMMs.  B (weights) live in LDS in FRAGMENT-MAJOR layout:
// element (col,k) at W'[(k>>5)*512 + ((k>>3)&3)*128 + col*8 + (k&7)],
// so a wave's b-fragment read is W' + kchunk*512 + lane*8 : 64 lanes read
// 1024 contiguous bytes -> conflict-free ds_read_b128.
template <int NC, int MT>
__device__ __forceinline__ void gemm_x(const short* __restrict__ A,
                                       const short* __restrict__ Wf,
                                       int kb32, int lane8, int kbase,
                                       int mbase, int col, int kq, float4v* acc)
{
#pragma unroll
    for (int kc = 0; kc < NC; ++kc) {
        const short8 b = *(const short8*)(Wf + (kb32 + kc) * 512 + lane8);
        const int k = kbase + kc * 32 + kq * 8;
#pragma unroll
        for (int mt = 0; mt < MT; ++mt) {
            const short8 a = *(const short8*)(A + (size_t)(mbase + mt * 16 + col) * IN_DIM + k);
            acc[mt] = __builtin_amdgcn_mfma_f32_16x16x32_bf16(a, b, acc[mt], 0, 0, 0);
        }
    }
}

template <int NC, int MT>
__device__ __forceinline__ void gemm_xf(const float* __restrict__ A,
                                        const short* __restrict__ Wf,
                                        int kb32, int lane8, int kbase,
                                        int mbase, int col, int kq, float4v* acc)
{
#pragma unroll
    for (int kc = 0; kc < NC; ++kc) {
        const short8 b = *(const short8*)(Wf + (kb32 + kc) * 512 + lane8);
        const int k = kbase + kc * 32 + kq * 8;
#pragma unroll
        for (int mt = 0; mt < MT; ++mt) {
            const float* ap = A + (size_t)(mbase + mt * 16 + col) * IN_DIM + k;
            const float4v a0 = *(const float4v*)ap;
            const float4v a1 = *(const float4v*)(ap + 4);
            short8 a;
            a[0] = f2bf(a0[0]); a[1] = f2bf(a0[1]); a[2] = f2bf(a0[2]); a[3] = f2bf(a0[3]);
            a[4] = f2bf(a1[0]); a[5] = f2bf(a1[1]); a[6] = f2bf(a1[2]); a[7] = f2bf(a1[3]);
            acc[mt] = __builtin_amdgcn_mfma_f32_16x16x32_bf16(a, b, acc[mt], 0, 0, 0);
        }
    }
}

// Cached-A GEMM, fused two weights (one A read feeds both accumulators).
template <int NC, int MT>
__device__ __forceinline__ void gemm_h2(const short* A,
                                        const short* __restrict__ Wf0,
                                        const short* __restrict__ Wf1,
                                        int kb32, int lane8, int kbase,
                                        int mbase, int col, int kq,
                                        float4v* acc0, float4v* acc1)
{
#pragma unroll
    for (int kc = 0; kc < NC; ++kc) {
        const short8 b0 = *(const short8*)(Wf0 + (kb32 + kc) * 512 + lane8);
        const short8 b1 = *(const short8*)(Wf1 + (kb32 + kc) * 512 + lane8);
        const int k = kbase + kc * 32 + kq * 8;
#pragma unroll
        for (int mt = 0; mt < MT; ++mt) {
            const short8 a = *(const short8*)(A + (size_t)(mbase + mt * 16 + col) * HID + k);
            acc0[mt] = __builtin_amdgcn_mfma_f32_16x16x32_bf16(a, b0, acc0[mt], 0, 0, 0);
            acc1[mt] = __builtin_amdgcn_mfma_f32_16x16x32_bf16(a, b1, acc1[mt], 0, 0, 0);
        }
    }
}

template <int NC, int MT>
__device__ __forceinline__ void gemm_h1(const short* A,
                                        const short* __restrict__ Wf,
                                        int kb32, int lane8, int kbase,
                                        int mbase, int col, int kq, float4v* acc)
{
#pragma unroll
    for (int kc = 0; kc < NC; ++kc) {
        const short8 b = *(const short8*)(Wf + (kb32 + kc) * 512 + lane8);
        const int k = kbase + kc * 32 + kq * 8;
#pragma unroll
        for (int mt = 0; mt < MT; ++mt) {
            const short8 a = *(const short8*)(A + (size_t)(mbase + mt * 16 + col) * HID + k);
            acc[mt] = __builtin_amdgcn_mfma_f32_16x16x32_bf16(a, b, acc[mt], 0, 0, 0);
        }
    }
}

__global__ void __launch_bounds__(NTHR, 1)
lstm_persistent(const float* __restrict__ xf,
                const float* __restrict__ Wi0, const float* __restrict__ Wh0,
                const float* __restrict__ bi0, const float* __restrict__ bh0,
                const float* __restrict__ Wi1, const float* __restrict__ Wh1,
                const float* __restrict__ bi1, const float* __restrict__ bh1,
                const float* __restrict__ h0in, const float* __restrict__ c0in,
                float* __restrict__ out,
                unsigned* __restrict__ bar,
                short* __restrict__ h0b,   // ws: [2][BH] bf16 L0 h dbuf
                short* __restrict__ h1b,   // ws: [2][BH] bf16 L1 h dbuf
                short* __restrict__ xbf,   // ws: [NX] bf16 x
                int use_pre)
{
    __shared__ short w0x[16 * 512];
    __shared__ short w0h[16 * 1024];
    __shared__ short w1x[16 * 1024];
    __shared__ short w1h[16 * 1024];
    __shared__ float gbuf[8][64][17];        // 8 K-partials
    __shared__ float bias0[16], bias1[16];
    __shared__ float cl0[64][4], cl1[64][4];

    const int wg    = blockIdx.x;
    const int tid   = threadIdx.x;
    const int wave  = tid >> 6;
    const int lane  = tid & 63;
    const int col   = lane & 15;
    const int kq    = lane >> 4;
    const int lane8 = lane * 8;
    const int mq    = wave >> 3;          // 0..1  M-half
    const int kk    = wave & 7;           // 0..7  K-eighth
    const int mb    = mq * 32;
    const int khb   = kk * 128;           // h-GEMM K base
    const int kb32h = kk * 4;
    const int kxb   = kk * 64;            // x-GEMM K base
    const int kb32x = kk * 2;
    const int u0    = wg << 2;
    const int b     = tid >> 2;           // only valid for tid < 256
    const int uu    = tid & 3;
    const int ug    = u0 + uu;
    const size_t ci = (size_t)b * HID + ug;

#define GROW(cc) ((size_t)((cc) >> 2) * HID + u0 + ((cc) & 3))
#define WOFF(k)  (((k) >> 5) * 512 + (((k) >> 3) & 3) * 128 + cc * 8 + ((k) & 7))
    for (int idx = tid; idx < 16 * 128; idx += NTHR) {
        const int cc = idx >> 7, ch = (idx & 127) << 2;
        const float4v v = *(const float4v*)(Wi0 + GROW(cc) * IN_DIM + ch);
        short4v s; s[0] = f2bf(v[0]); s[1] = f2bf(v[1]); s[2] = f2bf(v[2]); s[3] = f2bf(v[3]);
        *(short4v*)&w0x[WOFF(ch)] = s;
    }
    for (int idx = tid; idx < 16 * 256; idx += NTHR) {
        const int cc = idx >> 8, ch = (idx & 255) << 2;
        const size_t off = GROW(cc) * HID + ch;
        {
            const float4v v = *(const float4v*)(Wh0 + off);
            short4v s; s[0] = f2bf(v[0]); s[1] = f2bf(v[1]); s[2] = f2bf(v[2]); s[3] = f2bf(v[3]);
            *(short4v*)&w0h[WOFF(ch)] = s;
        }
        {
            const float4v v = *(const float4v*)(Wi1 + off);
            short4v s; s[0] = f2bf(v[0]); s[1] = f2bf(v[1]); s[2] = f2bf(v[2]); s[3] = f2bf(v[3]);
            *(short4v*)&w1x[WOFF(ch)] = s;
        }
        {
            const float4v v = *(const float4v*)(Wh1 + off);
            short4v s; s[0] = f2bf(v[0]); s[1] = f2bf(v[1]); s[2] = f2bf(v[2]); s[3] = f2bf(v[3]);
            *(short4v*)&w1h[WOFF(ch)] = s;
        }
    }
    if (tid < 16) {
        bias0[tid] = bi0[GROW(tid)] + bh0[GROW(tid)];
        bias1[tid] = bi1[GROW(tid)] + bh1[GROW(tid)];
    }
    if (tid < 256) {
        cl0[b][uu] = c0in[ci];
        cl1[b][uu] = c0in[BH + ci];
        h0b[BH + ci] = f2bf(h0in[ci]);        // plain; CG sync publishes
        h1b[BH + ci] = f2bf(h0in[BH + ci]);
    }

    if (wg == 0) {
        for (int i = tid; i < 320; i += NTHR)
            __hip_atomic_store(bar + i, 0u, RLX, AGT);
    }
    if (use_pre) {
        const size_t gtid = (size_t)blockIdx.x * NTHR + tid;
        for (size_t i = gtid * 4; i < NX; i += (size_t)NWG * NTHR * 4) {
            const float4v v = *(const float4v*)(xf + i);
            short4v s; s[0] = f2bf(v[0]); s[1] = f2bf(v[1]); s[2] = f2bf(v[2]); s[3] = f2bf(v[3]);
            *(short4v*)(xbf + i) = s;
        }
    }

    cg::grid_group grid = cg::this_grid();   // bootstrap: full release-acquire once
    __threadfence();
    grid.sync();
    __builtin_amdgcn_fence(__ATOMIC_ACQUIRE, "agent");  // cold caches for plain reads

    const float4v z = {0.f, 0.f, 0.f, 0.f};

    // x-partial for step 0 (register carry; recomputed each step in P3)
    float4v accL0c[2] = {z, z};
    if (use_pre)
        gemm_x<2, 2>(xbf, w0x, kb32x, lane8, kxb, mb, col, kq, accL0c);
    else
        gemm_xf<2, 2>(xf, w0x, kb32x, lane8, kxb, mb, col, kq, accL0c);

    // Events: X(s)=2s+1 arrive at step s (h0(s) published), waited at step s+1.
    //         Y(s)=2s+2 arrive at step s>=1 (h1(s-1) published), waited at s+1.
    for (int s = 0; s <= T_STEPS; ++s) {
        float4v accL0[2] = {accL0c[0], accL0c[1]};
        float4v accL1[2] = {z, z};

        if (s >= 1) {                      // ---- wait X: h0(s-1) visible ----
            if (tid == 0) {
                bar_wait(bar, 2u * (unsigned)s - 1u);
                __builtin_amdgcn_fence(__ATOMIC_ACQUIRE, "agent");  // one inv/CU/step
            }
            __syncthreads();
        }
        const short* h0p = h0b + (size_t)((s + 1) & 1) * BH;  // h0(s-1)
        const short* h1p = h1b + (size_t)(s & 1) * BH;        // h1(s-2)

        // ---- P1: GEMMs depending on h0(s-1) ----
        if (s < T_STEPS)
            gemm_h2<4, 2>(h0p, w0h, w1x, kb32h, lane8, khb, mb, col, kq, accL0, accL1);
        else
            gemm_h1<4, 2>(h0p, w1x, kb32h, lane8, khb, mb, col, kq, accL1);

        // ---- P2: L0 reduce + elementwise + publish h0(s) ----
        if (s < T_STEPS) {
#pragma unroll
            for (int mt = 0; mt < 2; ++mt)
#pragma unroll
                for (int r = 0; r < 4; ++r)
                    gbuf[kk][mb + mt * 16 + kq * 4 + r][col] = accL0[mt][r];
            __syncthreads();
            if (tid < 256) {
                float g4[4];
#pragma unroll
                for (int gi_ = 0; gi_ < 4; ++gi_) {
                    float v = bias0[gi_ * 4 + uu];
#pragma unroll
                    for (int p = 0; p < 8; ++p) v += gbuf[p][b][gi_ * 4 + uu];
                    g4[gi_] = v;
                }
                const float cn = sigmoidf_(g4[1]) * cl0[b][uu] + sigmoidf_(g4[0]) * tanhf(g4[2]);
                const float hn = sigmoidf_(g4[3]) * tanhf(cn);
                cl0[b][uu] = cn;
                cohstore_h(h0b + (size_t)(s & 1) * BH + ci, f2bf(hn));
            }
            __syncthreads();               // all stores drained (per-wave vmcnt)
            if (tid == 0) bar_arrive(bar, wg, 2u * (unsigned)s + 1u);
        }

        // ---- P3: x-GEMM prefetch for step s+1 (overlaps X propagation) ----
        if (s + 1 < T_STEPS) {
            accL0c[0] = z; accL0c[1] = z;
            if (use_pre)
                gemm_x<2, 2>(xbf + (size_t)(s + 1) * BATCH * IN_DIM, w0x,
                             kb32x, lane8, kxb, mb, col, kq, accL0c);
            else
                gemm_xf<2, 2>(xf + (size_t)(s + 1) * BATCH * IN_DIM, w0x,
                              kb32x, lane8, kxb, mb, col, kq, accL0c);
        }

        // ---- wait Y: h1(s-2) visible (no inv needed: X-inv this step covers) ----
        if (s >= 2) {
            if (tid == 0) bar_wait(bar, 2u * (unsigned)s);
            __syncthreads();
        }

        // ---- P4+P5: L1 GEMM + reduce + publish h1(s-1), out(t=s-1) ----
        if (s >= 1) {
            gemm_h1<4, 2>(h1p, w1h, kb32h, lane8, khb, mb, col, kq, accL1);
            const int t = s - 1;
#pragma unroll
            for (int mt = 0; mt < 2; ++mt)
#pragma unroll
                for (int r = 0; r < 4; ++r)
                    gbuf[kk][mb + mt * 16 + kq * 4 + r][col] = accL1[mt][r];
            __syncthreads();
            if (tid < 256) {
                float g4[4];
#pragma unroll
                for (int gi_ = 0; gi_ < 4; ++gi_) {
                    float v = bias1[gi_ * 4 + uu];
#pragma unroll
                    for (int p = 0; p < 8; ++p) v += gbuf[p][b][gi_ * 4 + uu];
                    g4[gi_] = v;
                }
                const float cn = sigmoidf_(g4[1]) * cl1[b][uu] + sigmoidf_(g4[0]) * tanhf(g4[2]);
                const float hn = sigmoidf_(g4[3]) * tanhf(cn);
                cl1[b][uu] = cn;
                cohstore_h(h1b + (size_t)(t & 1) * BH + ci, f2bf(hn));
                out[(size_t)t * BH + ci] = hn;
            }
            __syncthreads();               // stores drained
            if (s < T_STEPS)
                if (tid == 0) bar_arrive(bar, wg, 2u * (unsigned)s + 2u);
        }
    }

    if (tid < 256) {
        out[OPS_SZ + ci]                  = bf2f(cohload_h(h0b + (size_t)((T_STEPS - 1) & 1) * BH + ci));
        out[OPS_SZ + BH + ci]             = bf2f(cohload_h(h1b + (size_t)((T_STEPS - 1) & 1) * BH + ci));
        out[OPS_SZ + 2 * (size_t)BH + ci] = cl0[b][uu];
        out[OPS_SZ + 3 * (size_t)BH + ci] = cl1[b][uu];
    }
#undef GROW
#undef WOFF
}

extern "C" void kernel_launch(void* const* d_in, const int* in_sizes, int n_in,
                              void* d_out, int out_size, void* d_ws, size_t ws_size,
                              hipStream_t stream)
{
    const float* x    = (const float*)d_in[0];
    const float* h0   = (const float*)d_in[1];
    const float* c0   = (const float*)d_in[2];
    const float* Wi0  = (const float*)d_in[3];
    const float* Wh0  = (const float*)d_in[4];
    const float* bi0  = (const float*)d_in[5];
    const float* bh0  = (const float*)d_in[6];
    const float* Wi1  = (const float*)d_in[7];
    const float* Wh1  = (const float*)d_in[8];
    const float* bi1  = (const float*)d_in[9];
    const float* bh1  = (const float*)d_in[10];
    float* out = (float*)d_out;

    unsigned* bar = (unsigned*)d_ws;
    short* h0b = (short*)((char*)d_ws + BAR_BYTES);
    short* h1b = h0b + (size_t)2 * BH;
    short* xbf = h1b + (size_t)2 * BH;
    int use_pre = (ws_size >= BAR_BYTES + ((size_t)4 * BH + NX) * sizeof(short)) ? 1 : 0;

    void* args[] = {(void*)&x, (void*)&Wi0, (void*)&Wh0, (void*)&bi0, (void*)&bh0,
                    (void*)&Wi1, (void*)&Wh1, (void*)&bi1, (void*)&bh1,
                    (void*)&h0, (void*)&c0, (void*)&out,
                    (void*)&bar, (void*)&h0b, (void*)&h1b, (void*)&xbf, (void*)&use_pre};
    hipLaunchCooperativeKernel((void*)lstm_persistent, dim3(NWG), dim3(NTHR),
                               args, 0, stream);
}

// Round 4
// 6626.951 us; speedup vs baseline: 1.2302x; 1.2302x over previous
//
#include <hip/hip_runtime.h>
#include <hip/hip_cooperative_groups.h>
#include <cstdint>
#include <cstddef>

namespace cg = cooperative_groups;

typedef __attribute__((ext_vector_type(8))) short short8;
typedef __attribute__((ext_vector_type(4))) short short4v;
typedef __attribute__((ext_vector_type(4))) float float4v;

#define T_STEPS 512
#define BATCH   64
#define IN_DIM  512
#define HID     1024
#define BH      (BATCH * HID)              /* 65536 */
#define OPS_SZ  ((size_t)T_STEPS * BH)     /* 33554432 */
#define NX      ((size_t)T_STEPS * BATCH * IN_DIM) /* 16777216 */
#define NWG     256
#define NTHR    1024
#define BAR_BYTES 2048
#define RLX __ATOMIC_RELAXED
#define AGT __HIP_MEMORY_SCOPE_AGENT

__device__ __forceinline__ float bf2f(unsigned short b) {
    return __builtin_bit_cast(float, ((unsigned)b) << 16);
}
__device__ __forceinline__ short f2bf(float f) {
    unsigned u = __builtin_bit_cast(unsigned, f);
    unsigned r = (u + 0x7FFFu + ((u >> 16) & 1u)) >> 16;   // round-nearest-even
    return (short)(unsigned short)r;
}
// Fast activations: v_exp + v_rcp (~1e-7 rel err, far below bf16 rounding).
__device__ __forceinline__ float fsig(float v) {
    return __builtin_amdgcn_rcpf(1.0f + __expf(-v));
}
__device__ __forceinline__ float ftanh(float v) {
    return 2.0f * __builtin_amdgcn_rcpf(1.0f + __expf(-2.0f * v)) - 1.0f;
}

// h WRITE path: agent-scope (bypasses L1/L2, lands in L3 = coherence point).
__device__ __forceinline__ void cohstore_h(short* p, short v) {
    __hip_atomic_store((unsigned short*)p, (unsigned short)v, RLX, AGT);
}
__device__ __forceinline__ unsigned short cohload_h(const short* p) {
    return __hip_atomic_load((unsigned short*)p, RLX, AGT);
}

// ---- Single-event-per-step split barrier (monotone counters, R2-proven tree)
// bar dwords: sub[g] at g*32 (8 groups of 32 WGs, 128B apart); root at 256;
// go fan-out: 8 copies at 320+g*16 (64B apart) -> 32 pollers per line.
__device__ __forceinline__ void bar_arrive(unsigned* bar, int wg, unsigned e)
{
    // caller guarantees stores drained (post-__syncthreads => per-wave vmcnt(0))
    asm volatile("s_waitcnt vmcnt(0)" ::: "memory");
    __atomic_signal_fence(__ATOMIC_SEQ_CST);
    if (__hip_atomic_fetch_add(bar + (wg >> 5) * 32, 1u, RLX, AGT) == e * 32u - 1u)
        if (__hip_atomic_fetch_add(bar + 256, 1u, RLX, AGT) == e * 8u - 1u)
#pragma unroll
            for (int g = 0; g < 8; ++g)
                __hip_atomic_store(bar + 320 + g * 16, e, RLX, AGT);
}
__device__ __forceinline__ void bar_wait_inv(unsigned* bar, int wg, unsigned e)
{
    while (__hip_atomic_load(bar + 320 + (wg & 7) * 16, RLX, AGT) < e)
        __builtin_amdgcn_s_sleep(1);
    __builtin_amdgcn_fence(__ATOMIC_ACQUIRE, "agent");  // buffer_inv: L1+L2 clean drop
}

// ---- GEMMs.  Weights in LDS, FRAGMENT-MAJOR: element (cc,k) at
// W'[(k>>5)*512 + ((k>>3)&3)*128 + cc*8 + (k&7)]  ->  a wave's b-fragment read
// is W' + chunk*512 + lane*8: 1024 contiguous bytes, conflict-free ds_read_b128.
template <int NC>
__device__ __forceinline__ void gemm_x(const short* __restrict__ A,
                                       const short* __restrict__ Wf,
                                       int kb32, int lane8, int kbase,
                                       int mbase, int col, int kq, float4v* acc)
{
#pragma unroll
    for (int kc = 0; kc < NC; ++kc) {
        const short8 b = *(const short8*)(Wf + (kb32 + kc) * 512 + lane8);
        const int k = kbase + kc * 32 + kq * 8;
        const short8 a = *(const short8*)(A + (size_t)(mbase + col) * IN_DIM + k);
        acc[0] = __builtin_amdgcn_mfma_f32_16x16x32_bf16(a, b, acc[0], 0, 0, 0);
    }
}
template <int NC>
__device__ __forceinline__ void gemm_xf(const float* __restrict__ A,
                                        const short* __restrict__ Wf,
                                        int kb32, int lane8, int kbase,
                                        int mbase, int col, int kq, float4v* acc)
{
#pragma unroll
    for (int kc = 0; kc < NC; ++kc) {
        const short8 b = *(const short8*)(Wf + (kb32 + kc) * 512 + lane8);
        const int k = kbase + kc * 32 + kq * 8;
        const float* ap = A + (size_t)(mbase + col) * IN_DIM + k;
        const float4v a0 = *(const float4v*)ap;
        const float4v a1 = *(const float4v*)(ap + 4);
        short8 a;
        a[0] = f2bf(a0[0]); a[1] = f2bf(a0[1]); a[2] = f2bf(a0[2]); a[3] = f2bf(a0[3]);
        a[4] = f2bf(a1[0]); a[5] = f2bf(a1[1]); a[6] = f2bf(a1[2]); a[7] = f2bf(a1[3]);
        acc[0] = __builtin_amdgcn_mfma_f32_16x16x32_bf16(a, b, acc[0], 0, 0, 0);
    }
}
// Cached-A, fused two weights (one A read feeds both accumulators).
template <int NC>
__device__ __forceinline__ void gemm_h2(const short* A,
                                        const short* __restrict__ Wf0,
                                        const short* __restrict__ Wf1,
                                        int kb32, int lane8, int kbase,
                                        int mbase, int col, int kq,
                                        float4v* acc0, float4v* acc1)
{
#pragma unroll
    for (int kc = 0; kc < NC; ++kc) {
        const short8 b0 = *(const short8*)(Wf0 + (kb32 + kc) * 512 + lane8);
        const short8 b1 = *(const short8*)(Wf1 + (kb32 + kc) * 512 + lane8);
        const int k = kbase + kc * 32 + kq * 8;
        const short8 a = *(const short8*)(A + (size_t)(mbase + col) * HID + k);
        acc0[0] = __builtin_amdgcn_mfma_f32_16x16x32_bf16(a, b0, acc0[0], 0, 0, 0);
        acc1[0] = __builtin_amdgcn_mfma_f32_16x16x32_bf16(a, b1, acc1[0], 0, 0, 0);
    }
}
template <int NC>
__device__ __forceinline__ void gemm_h1(const short* A,
                                        const short* __restrict__ Wf,
                                        int kb32, int lane8, int kbase,
                                        int mbase, int col, int kq, float4v* acc)
{
#pragma unroll
    for (int kc = 0; kc < NC; ++kc) {
        const short8 b = *(const short8*)(Wf + (kb32 + kc) * 512 + lane8);
        const int k = kbase + kc * 32 + kq * 8;
        const short8 a = *(const short8*)(A + (size_t)(mbase + col) * HID + k);
        acc[0] = __builtin_amdgcn_mfma_f32_16x16x32_bf16(a, b, acc[0], 0, 0, 0);
    }
}

__global__ void __launch_bounds__(NTHR, 1)
lstm_persistent(const float* __restrict__ xf,
                const float* __restrict__ Wi0, const float* __restrict__ Wh0,
                const float* __restrict__ bi0, const float* __restrict__ bh0,
                const float* __restrict__ Wi1, const float* __restrict__ Wh1,
                const float* __restrict__ bi1, const float* __restrict__ bh1,
                const float* __restrict__ h0in, const float* __restrict__ c0in,
                float* __restrict__ out,
                unsigned* __restrict__ bar,
                short* __restrict__ h0b,   // ws: [2][BH] bf16 L0 h dbuf
                short* __restrict__ h1b,   // ws: [2][BH] bf16 L1 h dbuf
                short* __restrict__ xbf,   // ws: [NX] bf16 x
                int use_pre)
{
    __shared__ short w0x[16 * 512];
    __shared__ short w0h[16 * 1024];
    __shared__ short w1x[16 * 1024];
    __shared__ short w1h[16 * 1024];
    __shared__ __align__(16) float gbuf[4][64][20];  // 4 K-partials, gate-reordered cols, pad 20
    __shared__ __align__(16) float biasR0[16], biasR1[16];
    __shared__ float cl0[64][4], cl1[64][4];

    const int wg    = blockIdx.x;
    const int tid   = threadIdx.x;
    const int wave  = tid >> 6;
    const int lane  = tid & 63;
    const int col   = lane & 15;
    const int kq    = lane >> 4;
    const int lane8 = lane * 8;
    const int colR  = ((col & 3) << 2) | (col >> 2);   // gate-reordered output col
    const int mq    = wave >> 2;          // 0..3  M-quarter (16 rows)
    const int kk    = wave & 3;           // 0..3  K-quarter
    const int mb    = mq * 16;
    const int khb   = kk * 256;           // h-GEMM K base
    const int kb32h = kk * 8;
    const int kxb   = kk * 128;           // x-GEMM K base
    const int kb32x = kk * 4;
    const int u0    = wg << 2;
    const int b     = tid >> 2;           // only valid for tid < 256
    const int uu    = tid & 3;
    const int ug    = u0 + uu;
    const size_t ci = (size_t)b * HID + ug;

#define GROW(cc) ((size_t)((cc) >> 2) * HID + u0 + ((cc) & 3))
#define WOFF(k)  (((k) >> 5) * 512 + (((k) >> 3) & 3) * 128 + cc * 8 + ((k) & 7))
    for (int idx = tid; idx < 16 * 128; idx += NTHR) {
        const int cc = idx >> 7, ch = (idx & 127) << 2;
        const float4v v = *(const float4v*)(Wi0 + GROW(cc) * IN_DIM + ch);
        short4v s; s[0] = f2bf(v[0]); s[1] = f2bf(v[1]); s[2] = f2bf(v[2]); s[3] = f2bf(v[3]);
        *(short4v*)&w0x[WOFF(ch)] = s;
    }
    for (int idx = tid; idx < 16 * 256; idx += NTHR) {
        const int cc = idx >> 8, ch = (idx & 255) << 2;
        const size_t off = GROW(cc) * HID + ch;
        {
            const float4v v = *(const float4v*)(Wh0 + off);
            short4v s; s[0] = f2bf(v[0]); s[1] = f2bf(v[1]); s[2] = f2bf(v[2]); s[3] = f2bf(v[3]);
            *(short4v*)&w0h[WOFF(ch)] = s;
        }
        {
            const float4v v = *(const float4v*)(Wi1 + off);
            short4v s; s[0] = f2bf(v[0]); s[1] = f2bf(v[1]); s[2] = f2bf(v[2]); s[3] = f2bf(v[3]);
            *(short4v*)&w1x[WOFF(ch)] = s;
        }
        {
            const float4v v = *(const float4v*)(Wh1 + off);
            short4v s; s[0] = f2bf(v[0]); s[1] = f2bf(v[1]); s[2] = f2bf(v[2]); s[3] = f2bf(v[3]);
            *(short4v*)&w1h[WOFF(ch)] = s;
        }
    }
    if (tid < 16) {
        const int cc = tid;
        const int cr = ((cc & 3) << 2) | (cc >> 2);
        biasR0[cr] = bi0[GROW(cc)] + bh0[GROW(cc)];
        biasR1[cr] = bi1[GROW(cc)] + bh1[GROW(cc)];
    }
    if (tid < 256) {
        cl0[b][uu] = c0in[ci];
        cl1[b][uu] = c0in[BH + ci];
        h0b[BH + ci] = f2bf(h0in[ci]);        // plain; CG sync publishes
        h1b[BH + ci] = f2bf(h0in[BH + ci]);
    }

    if (wg == 0) {
        for (int i = tid; i < 512; i += NTHR)
            __hip_atomic_store(bar + i, 0u, RLX, AGT);
    }
    if (use_pre) {
        const size_t gtid = (size_t)blockIdx.x * NTHR + tid;
        for (size_t i = gtid * 4; i < NX; i += (size_t)NWG * NTHR * 4) {
            const float4v v = *(const float4v*)(xf + i);
            short4v s; s[0] = f2bf(v[0]); s[1] = f2bf(v[1]); s[2] = f2bf(v[2]); s[3] = f2bf(v[3]);
            *(short4v*)(xbf + i) = s;
        }
    }

    cg::grid_group grid = cg::this_grid();   // bootstrap: full release-acquire once
    __threadfence();
    grid.sync();
    __builtin_amdgcn_fence(__ATOMIC_ACQUIRE, "agent");  // cold caches for plain reads

    const float4v z = {0.f, 0.f, 0.f, 0.f};

    // One event per step: event s gates {h0(s-1), h1(s-2)}.  arrive(s+1) at
    // step-s end; x-GEMM(s) runs between arrive(s) and wait(s) -> release
    // propagation hides under it.
    for (int s = 0; s <= T_STEPS; ++s) {
        float4v accL0 = z, accL1 = z;

        if (s < T_STEPS) {
            if (use_pre)
                gemm_x<4>(xbf + (size_t)s * BATCH * IN_DIM, w0x,
                          kb32x, lane8, kxb, mb, col, kq, &accL0);
            else
                gemm_xf<4>(xf + (size_t)s * BATCH * IN_DIM, w0x,
                           kb32x, lane8, kxb, mb, col, kq, &accL0);
        }

        if (s > 0) {
            if (tid == 0) bar_wait_inv(bar, wg, (unsigned)s);
            __syncthreads();
        }
        const short* h0p = h0b + (size_t)((s + 1) & 1) * BH;  // h0(s-1)
        const short* h1p = h1b + (size_t)(s & 1) * BH;        // h1(s-2)

        // ---- h0-dependent GEMMs ----
        if (s < T_STEPS)
            gemm_h2<8>(h0p, w0h, w1x, kb32h, lane8, khb, mb, col, kq, &accL0, &accL1);
        else
            gemm_h1<8>(h0p, w1x, kb32h, lane8, khb, mb, col, kq, &accL1);

        // ---- h1 register prefetch (latency drains during reduce0) ----
        short8 a1[8];
        if (s >= 1) {
#pragma unroll
            for (int kc = 0; kc < 8; ++kc)
                a1[kc] = *(const short8*)(h1p + (size_t)(mb + col) * HID + khb + kc * 32 + kq * 8);
        }

        // ---- L0 reduce + elementwise + publish h0(s) ----
        if (s < T_STEPS) {
#pragma unroll
            for (int r = 0; r < 4; ++r)
                gbuf[kk][mb + kq * 4 + r][colR] = accL0[r];
            __syncthreads();
            if (tid < 256) {
                float4v g = *(const float4v*)&biasR0[uu * 4];
#pragma unroll
                for (int p = 0; p < 4; ++p)
                    g += *(const float4v*)&gbuf[p][b][uu * 4];
                const float cn = fsig(g[1]) * cl0[b][uu] + fsig(g[0]) * ftanh(g[2]);
                const float hn = fsig(g[3]) * ftanh(cn);
                cl0[b][uu] = cn;
                cohstore_h(h0b + (size_t)(s & 1) * BH + ci, f2bf(hn));
            }
            __syncthreads();               // gbuf reuse + store drain
        }

        // ---- L1: consume prefetched h1, reduce, publish h1(s-1) + out ----
        if (s >= 1) {
#pragma unroll
            for (int kc = 0; kc < 8; ++kc) {
                const short8 bw = *(const short8*)(w1h + (kb32h + kc) * 512 + lane8);
                accL1 = __builtin_amdgcn_mfma_f32_16x16x32_bf16(a1[kc], bw, accL1, 0, 0, 0);
            }
            const int t = s - 1;
#pragma unroll
            for (int r = 0; r < 4; ++r)
                gbuf[kk][mb + kq * 4 + r][colR] = accL1[r];
            __syncthreads();
            if (tid < 256) {
                float4v g = *(const float4v*)&biasR1[uu * 4];
#pragma unroll
                for (int p = 0; p < 4; ++p)
                    g += *(const float4v*)&gbuf[p][b][uu * 4];
                const float cn = fsig(g[1]) * cl1[b][uu] + fsig(g[0]) * ftanh(g[2]);
                const float hn = fsig(g[3]) * ftanh(cn);
                cl1[b][uu] = cn;
                cohstore_h(h1b + (size_t)(t & 1) * BH + ci, f2bf(hn));
                out[(size_t)t * BH + ci] = hn;
            }
            __syncthreads();               // stores drained (per-wave vmcnt(0))
        }

        if (s < T_STEPS && tid == 0)
            bar_arrive(bar, wg, (unsigned)s + 1u);
    }

    if (tid < 256) {
        out[OPS_SZ + ci]                  = bf2f(cohload_h(h0b + (size_t)((T_STEPS - 1) & 1) * BH + ci));
        out[OPS_SZ + BH + ci]             = bf2f(cohload_h(h1b + (size_t)((T_STEPS - 1) & 1) * BH + ci));
        out[OPS_SZ + 2 * (size_t)BH + ci] = cl0[b][uu];
        out[OPS_SZ + 3 * (size_t)BH + ci] = cl1[b][uu];
    }
#undef GROW
#undef WOFF
}

extern "C" void kernel_launch(void* const* d_in, const int* in_sizes, int n_in,
                              void* d_out, int out_size, void* d_ws, size_t ws_size,
                              hipStream_t stream)
{
    const float* x    = (const float*)d_in[0];
    const float* h0   = (const float*)d_in[1];
    const float* c0   = (const float*)d_in[2];
    const float* Wi0  = (const float*)d_in[3];
    const float* Wh0  = (const float*)d_in[4];
    const float* bi0  = (const float*)d_in[5];
    const float* bh0  = (const float*)d_in[6];
    const float* Wi1  = (const float*)d_in[7];
    const float* Wh1  = (const float*)d_in[8];
    const float* bi1  = (const float*)d_in[9];
    const float* bh1  = (const float*)d_in[10];
    float* out = (float*)d_out;

    unsigned* bar = (unsigned*)d_ws;
    short* h0b = (short*)((char*)d_ws + BAR_BYTES);
    short* h1b = h0b + (size_t)2 * BH;
    short* xbf = h1b + (size_t)2 * BH;
    int use_pre = (ws_size >= BAR_BYTES + ((size_t)4 * BH + NX) * sizeof(short)) ? 1 : 0;

    void* args[] = {(void*)&x, (void*)&Wi0, (void*)&Wh0, (void*)&bi0, (void*)&bh0,
                    (void*)&Wi1, (void*)&Wh1, (void*)&bi1, (void*)&bh1,
                    (void*)&h0, (void*)&c0, (void*)&out,
                    (void*)&bar, (void*)&h0b, (void*)&h1b, (void*)&xbf, (void*)&use_pre};
    hipLaunchCooperativeKernel((void*)lstm_persistent, dim3(NWG), dim3(NTHR),
                               args, 0, stream);
}

// Round 5
// 4856.174 us; speedup vs baseline: 1.6787x; 1.3646x over previous
//
#include <hip/hip_runtime.h>
#include <hip/hip_cooperative_groups.h>
#include <cstdint>
#include <cstddef>

namespace cg = cooperative_groups;

typedef __attribute__((ext_vector_type(8))) short short8;
typedef __attribute__((ext_vector_type(4))) short short4v;
typedef __attribute__((ext_vector_type(4))) float float4v;

#define T_STEPS 512
#define BATCH   64
#define IN_DIM  512
#define HID     1024
#define BH      (BATCH * HID)              /* 65536 */
#define OPS_SZ  ((size_t)T_STEPS * BH)     /* 33554432 */
#define NX      ((size_t)T_STEPS * BATCH * IN_DIM) /* 16777216 */
#define NWG     256
#define NTHR    1024
#define BAR_BYTES 8192                     /* 2048 dwords: X tree @0, Y tree @1024 */
#define RLX __ATOMIC_RELAXED
#define AGT __HIP_MEMORY_SCOPE_AGENT

__device__ __forceinline__ float bf2f(unsigned short b) {
    return __builtin_bit_cast(float, ((unsigned)b) << 16);
}
__device__ __forceinline__ short f2bf(float f) {
    unsigned u = __builtin_bit_cast(unsigned, f);
    unsigned r = (u + 0x7FFFu + ((u >> 16) & 1u)) >> 16;   // round-nearest-even
    return (short)(unsigned short)r;
}
// Fast activations: v_exp + v_rcp (~1e-7 rel err, far below bf16 rounding).
__device__ __forceinline__ float fsig(float v) {
    return __builtin_amdgcn_rcpf(1.0f + __expf(-v));
}
__device__ __forceinline__ float ftanh(float v) {
    return 2.0f * __builtin_amdgcn_rcpf(1.0f + __expf(-2.0f * v)) - 1.0f;
}

// h WRITE path: agent-scope (bypasses L1/L2, lands in L3 = coherence point).
__device__ __forceinline__ void cohstore_h(short* p, short v) {
    __hip_atomic_store((unsigned short*)p, (unsigned short)v, RLX, AGT);
}
__device__ __forceinline__ unsigned short cohload_h(const short* p) {
    return __hip_atomic_load((unsigned short*)p, RLX, AGT);
}

// ---- Monotone split barrier tree (R4-proven), parameterized by base.
// base dwords: sub[g] at g*32 (8 groups x 32 WGs, 128B apart); root at 256;
// go fan-out: 8 copies at 320+g*16 (64B apart) -> 32 pollers per line.
__device__ __forceinline__ void bar_arrive(unsigned* base, int wg, unsigned e)
{
    asm volatile("s_waitcnt vmcnt(0)" ::: "memory");   // publishes acked
    __atomic_signal_fence(__ATOMIC_SEQ_CST);
    if (__hip_atomic_fetch_add(base + (wg >> 5) * 32, 1u, RLX, AGT) == e * 32u - 1u)
        if (__hip_atomic_fetch_add(base + 256, 1u, RLX, AGT) == e * 8u - 1u)
#pragma unroll
            for (int g = 0; g < 8; ++g)
                __hip_atomic_store(base + 320 + g * 16, e, RLX, AGT);
}
__device__ __forceinline__ void bar_wait(unsigned* base, int wg, unsigned e)
{
    while (__hip_atomic_load(base + 320 + (wg & 7) * 16, RLX, AGT) < e)
        __builtin_amdgcn_s_sleep(1);
}

// ---- GEMM cores.  Both A (h/x, global, TILE layout) and W (LDS,
// fragment-major) step 512 shorts (=1024 B) per 32-k chunk; pointers are
// pre-offset per lane, so the wave reads 1024 CONTIGUOUS bytes per chunk
// from global (8 full 128-B lines) and 1024 contiguous from LDS.
template <int NC>
__device__ __forceinline__ void g1(const short* A, const short* __restrict__ W,
                                   float4v* acc)
{
#pragma unroll
    for (int kc = 0; kc < NC; ++kc) {
        const short8 a = *(const short8*)(A + kc * 512);
        const short8 b = *(const short8*)(W + kc * 512);
        acc[0] = __builtin_amdgcn_mfma_f32_16x16x32_bf16(a, b, acc[0], 0, 0, 0);
    }
}
template <int NC>
__device__ __forceinline__ void g2(const short* A, const short* __restrict__ W0,
                                   const short* __restrict__ W1,
                                   float4v* acc0, float4v* acc1)
{
#pragma unroll
    for (int kc = 0; kc < NC; ++kc) {
        const short8 a  = *(const short8*)(A + kc * 512);
        const short8 b0 = *(const short8*)(W0 + kc * 512);
        const short8 b1 = *(const short8*)(W1 + kc * 512);
        acc0[0] = __builtin_amdgcn_mfma_f32_16x16x32_bf16(a, b0, acc0[0], 0, 0, 0);
        acc1[0] = __builtin_amdgcn_mfma_f32_16x16x32_bf16(a, b1, acc1[0], 0, 0, 0);
    }
}
// fp32-A fallback (x not pre-converted): row-major gather, correctness path.
template <int NC>
__device__ __forceinline__ void gemm_xf(const float* __restrict__ A,
                                        const short* __restrict__ Wf,
                                        int kb32, int lane8, int kbase,
                                        int mbase, int col, int kq, float4v* acc)
{
#pragma unroll
    for (int kc = 0; kc < NC; ++kc) {
        const short8 b = *(const short8*)(Wf + (kb32 + kc) * 512 + lane8);
        const int k = kbase + kc * 32 + kq * 8;
        const float* ap = A + (size_t)(mbase + col) * IN_DIM + k;
        const float4v a0 = *(const float4v*)ap;
        const float4v a1 = *(const float4v*)(ap + 4);
        short8 a;
        a[0] = f2bf(a0[0]); a[1] = f2bf(a0[1]); a[2] = f2bf(a0[2]); a[3] = f2bf(a0[3]);
        a[4] = f2bf(a1[0]); a[5] = f2bf(a1[1]); a[6] = f2bf(a1[2]); a[7] = f2bf(a1[3]);
        acc[0] = __builtin_amdgcn_mfma_f32_16x16x32_bf16(a, b, acc[0], 0, 0, 0);
    }
}

__global__ void __launch_bounds__(NTHR, 1)
lstm_persistent(const float* __restrict__ xf,
                const float* __restrict__ Wi0, const float* __restrict__ Wh0,
                const float* __restrict__ bi0, const float* __restrict__ bh0,
                const float* __restrict__ Wi1, const float* __restrict__ Wh1,
                const float* __restrict__ bi1, const float* __restrict__ bh1,
                const float* __restrict__ h0in, const float* __restrict__ c0in,
                float* __restrict__ out,
                unsigned* __restrict__ bar,
                short* __restrict__ h0b,   // ws: [2][BH] bf16 L0 h dbuf (TILE layout)
                short* __restrict__ h1b,   // ws: [2][BH] bf16 L1 h dbuf (TILE layout)
                short* __restrict__ xbf,   // ws: [NX] bf16 x (TILE layout per step)
                int use_pre)
{
    __shared__ short w0x[16 * 512];
    __shared__ short w0h[16 * 1024];
    __shared__ short w1x[16 * 1024];
    __shared__ short w1h[16 * 1024];
    __shared__ __align__(16) float gbuf[4][64][20];  // 4 K-partials, gate-reordered cols
    __shared__ __align__(16) float biasR0[16], biasR1[16];
    __shared__ float cl0[64][4], cl1[64][4];

    const int wg    = blockIdx.x;
    const int tid   = threadIdx.x;
    const int wave  = tid >> 6;
    const int lane  = tid & 63;
    const int col   = lane & 15;
    const int kq    = lane >> 4;
    const int lane8 = lane * 8;
    const int aoff  = col * 32 + kq * 8;  // lane offset inside a 16x32 A-tile
    const int colR  = ((col & 3) << 2) | (col >> 2);   // gate-reordered output col
    const int mq    = wave >> 2;          // 0..3  M-quarter (16 batch rows)
    const int kk    = wave & 3;           // 0..3  K-quarter
    const int mb    = mq * 16;
    const int kb32h = kk * 8;             // h-GEMM k-chunk base (8 chunks of 32)
    const int kb32x = kk * 4;             // x-GEMM k-chunk base
    const int u0    = wg << 2;
    const int b     = tid >> 2;           // only valid for tid < 256
    const int uu    = tid & 3;
    const int ug    = u0 + uu;
    const size_t ci = (size_t)b * HID + ug;
    // tile-layout offset of element (batch b, unit ug) in an h buffer
    const int hoff  = ((b >> 4) << 14) + ((ug >> 5) << 9) + ((b & 15) << 5) + (ug & 31);

    unsigned* barX = bar;
    unsigned* barY = bar + 1024;

#define GROW(cc) ((size_t)((cc) >> 2) * HID + u0 + ((cc) & 3))
#define WOFF(k)  (((k) >> 5) * 512 + (((k) >> 3) & 3) * 128 + cc * 8 + ((k) & 7))
    for (int idx = tid; idx < 16 * 128; idx += NTHR) {
        const int cc = idx >> 7, ch = (idx & 127) << 2;
        const float4v v = *(const float4v*)(Wi0 + GROW(cc) * IN_DIM + ch);
        short4v s; s[0] = f2bf(v[0]); s[1] = f2bf(v[1]); s[2] = f2bf(v[2]); s[3] = f2bf(v[3]);
        *(short4v*)&w0x[WOFF(ch)] = s;
    }
    for (int idx = tid; idx < 16 * 256; idx += NTHR) {
        const int cc = idx >> 8, ch = (idx & 255) << 2;
        const size_t off = GROW(cc) * HID + ch;
        {
            const float4v v = *(const float4v*)(Wh0 + off);
            short4v s; s[0] = f2bf(v[0]); s[1] = f2bf(v[1]); s[2] = f2bf(v[2]); s[3] = f2bf(v[3]);
            *(short4v*)&w0h[WOFF(ch)] = s;
        }
        {
            const float4v v = *(const float4v*)(Wi1 + off);
            short4v s; s[0] = f2bf(v[0]); s[1] = f2bf(v[1]); s[2] = f2bf(v[2]); s[3] = f2bf(v[3]);
            *(short4v*)&w1x[WOFF(ch)] = s;
        }
        {
            const float4v v = *(const float4v*)(Wh1 + off);
            short4v s; s[0] = f2bf(v[0]); s[1] = f2bf(v[1]); s[2] = f2bf(v[2]); s[3] = f2bf(v[3]);
            *(short4v*)&w1h[WOFF(ch)] = s;
        }
    }
    if (tid < 16) {
        const int cc = tid;
        const int cr = ((cc & 3) << 2) | (cc >> 2);
        biasR0[cr] = bi0[GROW(cc)] + bh0[GROW(cc)];
        biasR1[cr] = bi1[GROW(cc)] + bh1[GROW(cc)];
    }
    if (tid < 256) {
        cl0[b][uu] = c0in[ci];
        cl1[b][uu] = c0in[BH + ci];
        h0b[BH + hoff] = f2bf(h0in[ci]);      // plain; CG sync publishes
        h1b[BH + hoff] = f2bf(h0in[BH + ci]);
    }

    if (wg == 0) {
        for (int i = tid; i < 2048; i += NTHR)
            __hip_atomic_store(bar + i, 0u, RLX, AGT);
    }
    if (use_pre) {   // x -> bf16, TILE layout [t][b/16][k/32][16][32]
        const size_t gtid = (size_t)blockIdx.x * NTHR + tid;
        for (size_t i = gtid * 4; i < NX; i += (size_t)NWG * NTHR * 4) {
            const float4v v = *(const float4v*)(xf + i);
            short4v s; s[0] = f2bf(v[0]); s[1] = f2bf(v[1]); s[2] = f2bf(v[2]); s[3] = f2bf(v[3]);
            const size_t t = i >> 15;
            const int rem = (int)(i & 32767);
            const int bb = rem >> 9, k = rem & 511;
            const size_t dst = (t << 15) + (size_t)((bb >> 4) << 13)
                             + ((k >> 5) << 9) + ((bb & 15) << 5) + (k & 31);
            *(short4v*)(xbf + dst) = s;
        }
    }

    cg::grid_group grid = cg::this_grid();   // bootstrap: full release-acquire once
    __threadfence();
    grid.sync();
    __builtin_amdgcn_fence(__ATOMIC_ACQUIRE, "agent");  // cold caches for plain reads

    const float4v z = {0.f, 0.f, 0.f, 0.f};

    // Events: X#(s+1) arrives MID-step s (h0(s) published); waited at step s+1
    // start -> ~2us of work (reduce1+elem1+xGEMM) covers its propagation.
    // Y#s arrives END-step s (h1(s-1) published); waited at step s+1 AFTER
    // gemm_h2 -> ~2us of work covers it.  Both waits are usually pre-satisfied.
    for (int s = 0; s <= T_STEPS; ++s) {
        float4v accL0 = z, accL1 = z;

        // ---- x-GEMM(s): no h dependency; overlaps X propagation ----
        if (s < T_STEPS) {
            if (use_pre)
                g1<4>(xbf + ((size_t)s << 15) + (mq << 13) + (kb32x << 9) + aoff,
                      w0x + kb32x * 512 + lane8, &accL0);
            else
                gemm_xf<4>(xf + ((size_t)s << 15), w0x, kb32x, lane8,
                           kk * 128, mb, col, kq, &accL0);
        }

        if (s > 0) {    // ---- wait X#s: h0(s-1) visible ----
            if (tid == 0) {
                bar_wait(barX, wg, (unsigned)s);
                __builtin_amdgcn_fence(__ATOMIC_ACQUIRE, "agent");  // one inv/CU/step
            }
            __syncthreads();
        }
        const short* h0p = h0b + (size_t)((s + 1) & 1) * BH;  // h0(s-1), tile layout
        const short* h1p = h1b + (size_t)(s & 1) * BH;        // h1(s-2), tile layout

        // ---- h0-dependent GEMMs ----
        if (s < T_STEPS)
            g2<8>(h0p + (mq << 14) + (kb32h << 9) + aoff,
                  w0h + kb32h * 512 + lane8, w1x + kb32h * 512 + lane8,
                  &accL0, &accL1);
        else
            g1<8>(h0p + (mq << 14) + (kb32h << 9) + aoff,
                  w1x + kb32h * 512 + lane8, &accL1);

        if (s >= 2) {   // ---- wait Y#(s-1): h1(s-2) visible (propagated under gemm) ----
            if (tid == 0) bar_wait(barY, wg, (unsigned)s - 1u);
            __syncthreads();
        }

        // ---- h1 register prefetch (latency drains during reduce0) ----
        short8 a1[8];
        if (s >= 1) {
            const short* hp = h1p + (mq << 14) + (kb32h << 9) + aoff;
#pragma unroll
            for (int kc = 0; kc < 8; ++kc)
                a1[kc] = *(const short8*)(hp + kc * 512);
        }

        // ---- L0 reduce + elementwise + publish h0(s) + ARRIVE X#(s+1) ----
        if (s < T_STEPS) {
#pragma unroll
            for (int r = 0; r < 4; ++r)
                gbuf[kk][mb + kq * 4 + r][colR] = accL0[r];
            __syncthreads();
            if (tid < 256) {
                float4v g = *(const float4v*)&biasR0[uu * 4];
#pragma unroll
                for (int p = 0; p < 4; ++p)
                    g += *(const float4v*)&gbuf[p][b][uu * 4];
                const float cn = fsig(g[1]) * cl0[b][uu] + fsig(g[0]) * ftanh(g[2]);
                const float hn = fsig(g[3]) * ftanh(cn);
                cl0[b][uu] = cn;
                cohstore_h(h0b + (size_t)(s & 1) * BH + hoff, f2bf(hn));
            }
            __syncthreads();               // gbuf reuse + all publishes drained
            if (tid == NTHR - 64)          // wave 15: no elem duties
                bar_arrive(barX, wg, (unsigned)s + 1u);
        }

        // ---- L1 MFMA + reduce + publish h1(s-1)+out + ARRIVE Y#s ----
        if (s >= 1) {
#pragma unroll
            for (int kc = 0; kc < 8; ++kc) {
                const short8 bw = *(const short8*)(w1h + (kb32h + kc) * 512 + lane8);
                accL1 = __builtin_amdgcn_mfma_f32_16x16x32_bf16(a1[kc], bw, accL1, 0, 0, 0);
            }
            const int t = s - 1;
#pragma unroll
            for (int r = 0; r < 4; ++r)
                gbuf[kk][mb + kq * 4 + r][colR] = accL1[r];
            __syncthreads();
            if (tid < 256) {
                float4v g = *(const float4v*)&biasR1[uu * 4];
#pragma unroll
                for (int p = 0; p < 4; ++p)
                    g += *(const float4v*)&gbuf[p][b][uu * 4];
                const float cn = fsig(g[1]) * cl1[b][uu] + fsig(g[0]) * ftanh(g[2]);
                const float hn = fsig(g[3]) * ftanh(cn);
                cl1[b][uu] = cn;
                cohstore_h(h1b + (size_t)(t & 1) * BH + hoff, f2bf(hn));
                out[(size_t)t * BH + ci] = hn;
            }
            __syncthreads();               // publishes drained
            if (s < T_STEPS && tid == NTHR - 64)
                bar_arrive(barY, wg, (unsigned)s);
        }
    }

    if (tid < 256) {
        out[OPS_SZ + ci]                  = bf2f(cohload_h(h0b + (size_t)((T_STEPS - 1) & 1) * BH + hoff));
        out[OPS_SZ + BH + ci]             = bf2f(cohload_h(h1b + (size_t)((T_STEPS - 1) & 1) * BH + hoff));
        out[OPS_SZ + 2 * (size_t)BH + ci] = cl0[b][uu];
        out[OPS_SZ + 3 * (size_t)BH + ci] = cl1[b][uu];
    }
#undef GROW
#undef WOFF
}

extern "C" void kernel_launch(void* const* d_in, const int* in_sizes, int n_in,
                              void* d_out, int out_size, void* d_ws, size_t ws_size,
                              hipStream_t stream)
{
    const float* x    = (const float*)d_in[0];
    const float* h0   = (const float*)d_in[1];
    const float* c0   = (const float*)d_in[2];
    const float* Wi0  = (const float*)d_in[3];
    const float* Wh0  = (const float*)d_in[4];
    const float* bi0  = (const float*)d_in[5];
    const float* bh0  = (const float*)d_in[6];
    const float* Wi1  = (const float*)d_in[7];
    const float* Wh1  = (const float*)d_in[8];
    const float* bi1  = (const float*)d_in[9];
    const float* bh1  = (const float*)d_in[10];
    float* out = (float*)d_out;

    unsigned* bar = (unsigned*)d_ws;
    short* h0b = (short*)((char*)d_ws + BAR_BYTES);
    short* h1b = h0b + (size_t)2 * BH;
    short* xbf = h1b + (size_t)2 * BH;
    int use_pre = (ws_size >= BAR_BYTES + ((size_t)4 * BH + NX) * sizeof(short)) ? 1 : 0;

    void* args[] = {(void*)&x, (void*)&Wi0, (void*)&Wh0, (void*)&bi0, (void*)&bh0,
                    (void*)&Wi1, (void*)&Wh1, (void*)&bi1, (void*)&bh1,
                    (void*)&h0, (void*)&c0, (void*)&out,
                    (void*)&bar, (void*)&h0b, (void*)&h1b, (void*)&xbf, (void*)&use_pre};
    hipLaunchCooperativeKernel((void*)lstm_persistent, dim3(NWG), dim3(NTHR),
                               args, 0, stream);
}